// Round 7
// baseline (97.309 us; speedup 1.0000x reference)
//
#include <hip/hip_runtime.h>
#include <math.h>

// CrossEntropyLabelSmooth — quarter-row version.
// kernel1: 16384 blocks, each does a QUARTER row (32 KB stream, 2000 float4).
//          Per thread: 7 unguarded float4 loads issued upfront (7-deep MLP)
//          + 1 guarded tail load. Writes per-row partials {s_q, sx_q} into
//          rw[row][16]; quarter-0 block also writes xt and possum.
// kernel2: one 1024-thread block combines partials into per-row loss and
//          tree-reduces (fixed order, deterministic).
//
// loss_i = -( A*(x_t - lse) + C1*(sumx - C*lse) + C2*(possum - P*lse) )
//   A = 0.89, C1 = (1-w)*eps/C, C2 = w*lambda/P
//
// Ledger: nt-loads -2.7x; per-block agent-scope acq_rel fusion -1.8x;
// VALU cuts ~0; 4-deep MLP +1.5%; half-row + light epilogue + fat k2 +4%.
// This round: 32KB work quantum (finer dynamic balance vs L3-hit variance)
// + 7-deep upfront load batch.

#define NB 4096      // B
#define NC 32000     // C
#define NP 50        // P
#define NF4Q 2000    // float4 per QUARTER row

typedef float f4 __attribute__((ext_vector_type(4)));

#define CONSUME(v)                                                        \
    e0 += __expf((v).x); e1 += __expf((v).y);                             \
    e2 += __expf((v).z); e3 += __expf((v).w);                             \
    t0 += (v).x; t1 += (v).y; t2 += (v).z; t3 += (v).w;

__global__ __launch_bounds__(256) void row_quarter_kernel(
    const float* __restrict__ x,
    const int*   __restrict__ targets,
    const int*   __restrict__ posvid,
    float*       __restrict__ rw)   // [NB][16]: s0..s3, sx0..sx3, xt, g, pad
{
    const int row = blockIdx.x >> 2;
    const int q   = blockIdx.x & 3;
    const int tid = threadIdx.x;
    const float* __restrict__ xr = x + (size_t)row * NC;
    const f4*    __restrict__ x4 = (const f4*)xr + q * NF4Q;

    float e0 = 0.0f, e1 = 0.0f, e2 = 0.0f, e3 = 0.0f;
    float t0 = 0.0f, t1 = 0.0f, t2 = 0.0f, t3 = 0.0f;

    // ---- 7 unguarded loads issued upfront (2000 = 7*256 + 208) ----
    {
        f4 a0 = x4[tid];
        f4 a1 = x4[tid + 1 * 256];
        f4 a2 = x4[tid + 2 * 256];
        f4 a3 = x4[tid + 3 * 256];
        f4 a4 = x4[tid + 4 * 256];
        f4 a5 = x4[tid + 5 * 256];
        f4 a6 = x4[tid + 6 * 256];
        CONSUME(a0) CONSUME(a1) CONSUME(a2) CONSUME(a3)
        CONSUME(a4) CONSUME(a5) CONSUME(a6)
        if (tid < NF4Q - 7 * 256) {            // 208 lanes
            f4 a7 = x4[tid + 7 * 256];
            CONSUME(a7)
        }
    }

    float s    = (e0 + e1) + (e2 + e3);
    float sumx = (t0 + t1) + (t2 + t3);

    // ---- cheap epilogue: wave shuffle reduce, then 4-value LDS combine ----
    const int lane = tid & 63;
    const int wid  = tid >> 6;
#pragma unroll
    for (int off = 32; off > 0; off >>= 1) {
        s    += __shfl_down(s, off, 64);
        sumx += __shfl_down(sumx, off, 64);
    }
    __shared__ float ls[4], lx[4];
    if (lane == 0) { ls[wid] = s; lx[wid] = sumx; }

    // ---- gather of positives (quarter-0 block only) overlaps the barrier ----
    float g = 0.0f;
    if (q == 0 && tid < NP) {
        int c = posvid[(size_t)row * NP + tid];
        g = xr[c];
    }
    __syncthreads();

    if (q == 0 && tid < 64) {
#pragma unroll
        for (int off = 32; off > 0; off >>= 1)
            g += __shfl_down(g, off, 64);
    }

    if (tid == 0) {
        float S  = (ls[0] + ls[1]) + (ls[2] + ls[3]);
        float SX = (lx[0] + lx[1]) + (lx[2] + lx[3]);
        float* r16 = rw + (size_t)row * 16;
        r16[q]     = S;
        r16[4 + q] = SX;
        if (q == 0) {
            r16[8] = xr[targets[row]];
            r16[9] = g;
        }
    }
}

// Single 1024-thread block: per-row loss from partials, fixed-order reduce.
__global__ __launch_bounds__(1024) void combine_kernel(
    const float* __restrict__ rw, float* __restrict__ out)
{
    const int tid = threadIdx.x;
    const f4* __restrict__ w4 = (const f4*)rw;

    const float EPSILON     = 0.1f;
    const float SOFT_WEIGHT = 0.1f;
    const float SOFT_LAMBDA = 0.2f;
    const float A  = (1.0f - SOFT_WEIGHT) * (1.0f - EPSILON)
                   + SOFT_WEIGHT * (1.0f - SOFT_LAMBDA);      // 0.89
    const float C1 = (1.0f - SOFT_WEIGHT) * EPSILON / (float)NC;
    const float C2 = SOFT_WEIGHT * SOFT_LAMBDA / (float)NP;

    float acc = 0.0f;
    for (int r = tid; r < NB; r += 1024) {
        f4 a = w4[4 * r];       // s0..s3
        f4 b = w4[4 * r + 1];   // sx0..sx3
        f4 c = w4[4 * r + 2];   // xt, g, pad, pad
        float lse  = logf((a.x + a.y) + (a.z + a.w));
        float sumx = (b.x + b.y) + (b.z + b.w);
        acc += -( A  * (c.x - lse)
                + C1 * (sumx - (float)NC * lse)
                + C2 * (c.y  - (float)NP * lse) );
    }

    const int lane = tid & 63;
    const int wid  = tid >> 6;          // 16 waves
#pragma unroll
    for (int off = 32; off > 0; off >>= 1)
        acc += __shfl_down(acc, off, 64);

    __shared__ float red[16];
    if (lane == 0) red[wid] = acc;
    __syncthreads();

    if (tid < 16) {
        float v = red[tid];
#pragma unroll
        for (int off = 8; off > 0; off >>= 1)
            v += __shfl_down(v, off, 16);
        if (tid == 0) out[0] = v * (1.0f / (float)NB);
    }
}

extern "C" void kernel_launch(void* const* d_in, const int* in_sizes, int n_in,
                              void* d_out, int out_size, void* d_ws, size_t ws_size,
                              hipStream_t stream)
{
    const float* x       = (const float*)d_in[0];
    const int*   targets = (const int*)d_in[1];
    const int*   posvid  = (const int*)d_in[2];
    float*       out     = (float*)d_out;
    float*       rw      = (float*)d_ws;   // NB*16 floats of per-row partials

    row_quarter_kernel<<<4 * NB, 256, 0, stream>>>(x, targets, posvid, rw);
    combine_kernel<<<1, 1024, 0, stream>>>(rw, out);
}

// Round 8
// 95.925 us; speedup vs baseline: 1.0144x; 1.0144x over previous
//
#include <hip/hip_runtime.h>
#include <math.h>

// CrossEntropyLabelSmooth — row-split version (r6 optimum, reverted from r7).
// kernel1: 8192 blocks, each does HALF a row (64 KB stream), writes per-row
//          partials {s_half, sumx_half} (+ xt, possum from the half-0 block).
// kernel2: one 1024-thread block combines partials into per-row loss and
//          tree-reduces (fixed order, deterministic).
//
// loss_i = -( A*(x_t - lse) + C1*(sumx - C*lse) + C2*(possum - P*lse) )
//   A = 0.89, C1 = (1-w)*eps/C, C2 = w*lambda/P
//
// Ledger: nt-loads -2.7x; per-block agent-scope acq_rel fusion -1.8x;
// VALU cuts ~0; 4-deep MLP +1.5%; half-row + light epilogue + fat k2 +4%;
// quarter-row split -1.4% (overhead > balance gain). 64KB quantum optimal.

#define NB 4096      // B
#define NC 32000     // C
#define NP 50        // P
#define NF4H 4000    // float4 per HALF row

typedef float f4 __attribute__((ext_vector_type(4)));

__global__ __launch_bounds__(256) void row_half_kernel(
    const float* __restrict__ x,
    const int*   __restrict__ targets,
    const int*   __restrict__ posvid,
    float*       __restrict__ rw)        // [NB][8]: s0,s1,sx0,sx1,xt,g,pad,pad
{
    const int row  = blockIdx.x >> 1;
    const int half = blockIdx.x & 1;
    const int tid  = threadIdx.x;
    const float* __restrict__ xr = x + (size_t)row * NC;
    const f4*    __restrict__ x4 = (const f4*)xr + half * NF4H;

    float e0 = 0.0f, e1 = 0.0f, e2 = 0.0f, e3 = 0.0f;
    float t0 = 0.0f, t1 = 0.0f, t2 = 0.0f, t3 = 0.0f;

    // ---- main stream: batches of 4 independent float4 loads ----
    int idx = tid;
    for (; idx + 3 * 256 < NF4H; idx += 4 * 256) {
        f4 a = x4[idx];
        f4 b = x4[idx + 256];
        f4 c = x4[idx + 512];
        f4 d = x4[idx + 768];

        e0 += __expf(a.x); e1 += __expf(a.y); e2 += __expf(a.z); e3 += __expf(a.w);
        t0 += a.x;         t1 += a.y;         t2 += a.z;         t3 += a.w;
        e0 += __expf(b.x); e1 += __expf(b.y); e2 += __expf(b.z); e3 += __expf(b.w);
        t0 += b.x;         t1 += b.y;         t2 += b.z;         t3 += b.w;
        e0 += __expf(c.x); e1 += __expf(c.y); e2 += __expf(c.z); e3 += __expf(c.w);
        t0 += c.x;         t1 += c.y;         t2 += c.z;         t3 += c.w;
        e0 += __expf(d.x); e1 += __expf(d.y); e2 += __expf(d.z); e3 += __expf(d.w);
        t0 += d.x;         t1 += d.y;         t2 += d.z;         t3 += d.w;
    }
    for (; idx < NF4H; idx += 256) {
        f4 a = x4[idx];
        e0 += __expf(a.x); e1 += __expf(a.y); e2 += __expf(a.z); e3 += __expf(a.w);
        t0 += a.x;         t1 += a.y;         t2 += a.z;         t3 += a.w;
    }

    float s    = (e0 + e1) + (e2 + e3);
    float sumx = (t0 + t1) + (t2 + t3);

    // ---- cheap epilogue: wave shuffle reduce, then 4-value LDS combine ----
    const int lane = tid & 63;
    const int wid  = tid >> 6;
#pragma unroll
    for (int off = 32; off > 0; off >>= 1) {
        s    += __shfl_down(s, off, 64);
        sumx += __shfl_down(sumx, off, 64);
    }
    __shared__ float ls[4], lx[4];
    if (lane == 0) { ls[wid] = s; lx[wid] = sumx; }

    // ---- gather of positives (half-0 block only), overlaps the barrier ----
    float g = 0.0f;
    if (half == 0 && tid < NP) {
        int c = posvid[(size_t)row * NP + tid];
        g = xr[c];
    }
    __syncthreads();

    if (half == 0 && tid < 64) {
#pragma unroll
        for (int off = 32; off > 0; off >>= 1)
            g += __shfl_down(g, off, 64);
    }

    if (tid == 0) {
        float S  = (ls[0] + ls[1]) + (ls[2] + ls[3]);
        float SX = (lx[0] + lx[1]) + (lx[2] + lx[3]);
        float* r8 = rw + (size_t)row * 8;
        r8[half]     = S;
        r8[2 + half] = SX;
        if (half == 0) {
            r8[4] = xr[targets[row]];
            r8[5] = g;
        }
    }
}

// Single 1024-thread block: per-row loss from partials, fixed-order reduce.
__global__ __launch_bounds__(1024) void combine_kernel(
    const float* __restrict__ rw, float* __restrict__ out)
{
    const int tid = threadIdx.x;
    const f4* __restrict__ w4 = (const f4*)rw;

    const float EPSILON     = 0.1f;
    const float SOFT_WEIGHT = 0.1f;
    const float SOFT_LAMBDA = 0.2f;
    const float A  = (1.0f - SOFT_WEIGHT) * (1.0f - EPSILON)
                   + SOFT_WEIGHT * (1.0f - SOFT_LAMBDA);      // 0.89
    const float C1 = (1.0f - SOFT_WEIGHT) * EPSILON / (float)NC;
    const float C2 = SOFT_WEIGHT * SOFT_LAMBDA / (float)NP;

    float acc = 0.0f;
    for (int r = tid; r < NB; r += 1024) {
        f4 a = w4[2 * r];       // s0, s1, sx0, sx1
        f4 b = w4[2 * r + 1];   // xt, g, pad, pad
        float lse  = logf(a.x + a.y);
        float sumx = a.z + a.w;
        acc += -( A  * (b.x - lse)
                + C1 * (sumx - (float)NC * lse)
                + C2 * (b.y  - (float)NP * lse) );
    }

    const int lane = tid & 63;
    const int wid  = tid >> 6;          // 16 waves
#pragma unroll
    for (int off = 32; off > 0; off >>= 1)
        acc += __shfl_down(acc, off, 64);

    __shared__ float red[16];
    if (lane == 0) red[wid] = acc;
    __syncthreads();

    if (tid < 16) {
        float v = red[tid];
#pragma unroll
        for (int off = 8; off > 0; off >>= 1)
            v += __shfl_down(v, off, 16);
        if (tid == 0) out[0] = v * (1.0f / (float)NB);
    }
}

extern "C" void kernel_launch(void* const* d_in, const int* in_sizes, int n_in,
                              void* d_out, int out_size, void* d_ws, size_t ws_size,
                              hipStream_t stream)
{
    const float* x       = (const float*)d_in[0];
    const int*   targets = (const int*)d_in[1];
    const int*   posvid  = (const int*)d_in[2];
    float*       out     = (float*)d_out;
    float*       rw      = (float*)d_ws;   // NB*8 floats of per-row partials

    row_half_kernel<<<2 * NB, 256, 0, stream>>>(x, targets, posvid, rw);
    combine_kernel<<<1, 1024, 0, stream>>>(rw, out);
}